// Round 13
// baseline (694.971 us; speedup 1.0000x reference)
//
#include <hip/hip_runtime.h>
#include <hip/hip_bf16.h>
#include <stdint.h>

#define N_LEVELS   16
#define LOG2_T     19
#define TABLE_SIZE (1u << LOG2_T)
#define PRIME_Y    2654435761u
#define PRIME_Z    805459861u

#define NB        32768     // 32^3 Morton buckets
#define SORT_B    256       // sort blocks (each owns a contiguous point chunk)

typedef float v4f __attribute__((ext_vector_type(4)));
typedef _Float16 v8h __attribute__((ext_vector_type(8)));

// ---------------- Morton key, 3x5 bits (bucketing only) ----------------
__device__ __forceinline__ uint32_t part1by2(uint32_t v) {
    v &= 0x3FFu;
    v = (v | (v << 16)) & 0x030000FFu;
    v = (v | (v <<  8)) & 0x0300F00Fu;
    v = (v | (v <<  4)) & 0x030C30C3u;
    v = (v | (v <<  2)) & 0x09249249u;
    return v;
}
__device__ __forceinline__ uint32_t morton_key(float xr, float yr, float zr) {
    int vx = (int)((xr * 0.5f + 0.5f) * 32.0f);
    int vy = (int)((yr * 0.5f + 0.5f) * 32.0f);
    int vz = (int)((zr * 0.5f + 0.5f) * 32.0f);
    vx = vx < 0 ? 0 : (vx > 31 ? 31 : vx);
    vy = vy < 0 ? 0 : (vy > 31 ? 31 : vy);
    vz = vz < 0 ? 0 : (vz > 31 ? 31 : vz);
    return part1by2((uint32_t)vx) | (part1by2((uint32_t)vy) << 1)
         | (part1by2((uint32_t)vz) << 2);   // 15-bit key
}

// ============== sort, NO device atomics (LDS-histogram counting sort) =====
// 256 threads/block (measured best in R11/R13 A-B: these kernels are
// LDS-pipe-bound, ~40k LDS ops/block floor; 1024 threads regressed).
__global__ __launch_bounds__(256)
void hist_kernel(const float* __restrict__ x, uint32_t* __restrict__ g_hist,
                 int n, int chunk)
{
    __shared__ uint32_t pack[NB / 2];
    const int b = blockIdx.x, t = threadIdx.x;
    for (int w = t; w < NB / 2; w += 256) pack[w] = 0;
    __syncthreads();
    const int beg = b * chunk;
    const int end = (beg + chunk < n) ? (beg + chunk) : n;
    for (int i = beg + t; i < end; i += 256) {
        const uint32_t key = morton_key(x[3*i], x[3*i+1], x[3*i+2]);
        atomicAdd(&pack[key >> 1], 1u << ((key & 1u) << 4));
    }
    __syncthreads();
    uint32_t* __restrict__ dst = g_hist + (size_t)b * NB;
    for (int w = t; w < NB / 2; w += 256) {
        const uint32_t p = pack[w];
        dst[2*w]     = p & 0xFFFFu;
        dst[2*w + 1] = p >> 16;
    }
}

// column scan: part[b][key] = sum_{b'<b} hist[b'][key]; totals[key] = full sum
__global__ __launch_bounds__(256)
void scan_cols_kernel(const uint32_t* __restrict__ g_hist,
                      uint32_t* __restrict__ g_part,
                      uint32_t* __restrict__ totals)
{
    const int key = blockIdx.x * 256 + threadIdx.x;   // 0..NB-1
    uint32_t run = 0;
    #pragma unroll 8
    for (int b = 0; b < SORT_B; ++b) {
        const size_t idx = (size_t)b * NB + key;
        const uint32_t v = g_hist[idx];
        g_part[idx] = run;
        run += v;
    }
    totals[key] = run;
}

// fused full exclusive scan of totals[NB] -> base[NB], single block
__global__ __launch_bounds__(1024)
void scan_full_kernel(const uint32_t* __restrict__ totals,
                      uint32_t* __restrict__ base)
{
    __shared__ uint32_t s[1024];
    const int t = threadIdx.x;
    const int beg = t * (NB / 1024);          // 32 keys per thread
    uint32_t loc[NB / 1024];
    #pragma unroll
    for (int k = 0; k < NB / 1024; ++k) loc[k] = totals[beg + k];
    uint32_t sum = 0;
    #pragma unroll
    for (int k = 0; k < NB / 1024; ++k) { const uint32_t v = loc[k]; loc[k] = sum; sum += v; }
    s[t] = sum; __syncthreads();
    for (int d = 1; d < 1024; d <<= 1) {
        const uint32_t u = (t >= d) ? s[t - d] : 0;
        __syncthreads();
        s[t] += u;
        __syncthreads();
    }
    const uint32_t excl = s[t] - sum;
    #pragma unroll
    for (int k = 0; k < NB / 1024; ++k) base[beg + k] = loc[k] + excl;
}

// scatter: rank from LDS counters; pos = base+part+rank.
// Writes xs (SoA) + pid[pos] = original index (sorted -> orig map).
__global__ __launch_bounds__(256)
void scatter_kernel(const float* __restrict__ x,
                    const uint32_t* __restrict__ base,
                    const uint32_t* __restrict__ g_part,
                    float* __restrict__ xs,        // [3][N]
                    int* __restrict__ pid,         // [N] sorted -> orig
                    int n, int chunk)
{
    __shared__ uint32_t pack[NB / 2];
    const int b = blockIdx.x, t = threadIdx.x;
    for (int w = t; w < NB / 2; w += 256) pack[w] = 0;
    __syncthreads();
    const uint32_t* __restrict__ part = g_part + (size_t)b * NB;
    const int beg = b * chunk;
    const int end = (beg + chunk < n) ? (beg + chunk) : n;
    for (int i = beg + t; i < end; i += 256) {
        const float a = x[3*i], c = x[3*i+1], d = x[3*i+2];
        const uint32_t key = morton_key(a, c, d);
        const uint32_t sh = (key & 1u) << 4;
        uint32_t r = atomicAdd(&pack[key >> 1], 1u << sh);
        r = (r >> sh) & 0xFFFFu;
        const uint32_t pos = base[key] + part[key] + r;
        xs[pos]       = a;
        xs[n + pos]   = c;
        xs[2*n + pos] = d;
        pid[pos]      = i;
    }
}

// ============================ encode ============================
// Unchanged since R10 (level-major, x-corner pair merging, sorted input,
// f16 x256 output). At the L2 request-rate floor for 32^3 locality:
// ~105M merged requests / 128 req/cyc / 2.4 GHz = ~342 us (validated 3x).
__global__ __launch_bounds__(256, 8)
void encode_kernel(const float* __restrict__ xs,          // [3][N] sorted
                   const float* __restrict__ tables,      // [16, T, 2]
                   const float* __restrict__ resolutions, // [16]
                   _Float16* __restrict__ a_ws,           // [32][N] f16, x256
                   int n)
{
    const int l = blockIdx.y;
    int p = blockIdx.x * blockDim.x + threadIdx.x;
    if (p >= n) p = n - 1;

    const float x0 = xs[p]       * 0.5f + 0.5f;
    const float x1 = xs[n + p]   * 0.5f + 0.5f;
    const float x2 = xs[2*n + p] * 0.5f + 0.5f;

    const float res = resolutions[l];
    const float px = x0 * res, py = x1 * res, pz = x2 * res;
    const float fx = floorf(px), fy = floorf(py), fz = floorf(pz);
    const float wx = px - fx, wy = py - fy, wz = pz - fz;
    const uint32_t cx = (uint32_t)fx;
    const uint32_t cy = (uint32_t)fy;
    const uint32_t cz = (uint32_t)fz;

    const uint32_t hy0 = cy * PRIME_Y, hy1 = hy0 + PRIME_Y;
    const uint32_t hz0 = cz * PRIME_Z, hz1 = hz0 + PRIME_Z;

    const float wx0 = 1.0f - wx, wy0 = 1.0f - wy, wz0 = 1.0f - wz;

    const float* __restrict__ tab = tables + (size_t)l * (size_t)TABLE_SIZE * 2u;

    const uint32_t hyz[4] = { hy0 ^ hz0, hy1 ^ hz0, hy0 ^ hz1, hy1 ^ hz1 };

    float2 cva[4], cvb[4];

    if ((cx & 1u) == 0u) {
        #pragma unroll
        for (int q = 0; q < 4; ++q) {
            const uint32_t idx_a = (cx ^ hyz[q]) & (TABLE_SIZE - 1u);
            const uint32_t base  = idx_a & ~1u;
            const float4 f4 = *(const float4*)(tab + 2u * base);
            const bool hi = (idx_a & 1u) != 0u;
            cva[q] = hi ? make_float2(f4.z, f4.w) : make_float2(f4.x, f4.y);
            cvb[q] = hi ? make_float2(f4.x, f4.y) : make_float2(f4.z, f4.w);
        }
    } else {
        const uint32_t hx0 = cx, hx1 = cx + 1u;
        #pragma unroll
        for (int q = 0; q < 4; ++q) {
            const uint32_t idx_a = (hx0 ^ hyz[q]) & (TABLE_SIZE - 1u);
            const uint32_t idx_b = (hx1 ^ hyz[q]) & (TABLE_SIZE - 1u);
            cva[q] = *(const float2*)(tab + 2u * idx_a);
            cvb[q] = *(const float2*)(tab + 2u * idx_b);
        }
    }

    float f0 = 0.0f, f1 = 0.0f;
    #pragma unroll
    for (int q = 0; q < 4; ++q) {
        const float yf = (q & 1) ? wy : wy0;
        const float zf = (q & 2) ? wz : wz0;
        const float wgt_a = (wx0 * yf) * zf;
        const float wgt_b = (wx  * yf) * zf;
        f0 = fmaf(wgt_a, cva[q].x, f0);
        f1 = fmaf(wgt_a, cva[q].y, f1);
        f0 = fmaf(wgt_b, cvb[q].x, f0);
        f1 = fmaf(wgt_b, cvb[q].y, f1);
    }

    a_ws[(size_t)(2 * l + 0) * n + p] = (_Float16)(f0 * 256.0f);
    a_ws[(size_t)(2 * l + 1) * n + p] = (_Float16)(f1 * 256.0f);
}

// ============================ MFMA MLP ============================
// R11 structure; writes out[pid[p]] directly (no unscatter kernel).
__global__ __launch_bounds__(256, 2)
void mlp_mfma_kernel(const _Float16* __restrict__ a_ws,  // [32][N] f16 x256
                     const int* __restrict__ pid,        // [N] sorted->orig
                     const float* __restrict__ W1,
                     const float* __restrict__ b1,
                     const float* __restrict__ W2,
                     const float* __restrict__ b2,
                     const float* __restrict__ W3,
                     const float* __restrict__ b3,
                     float* __restrict__ out,
                     int n)
{
    __shared__ float lds[4 * 64 * 16];

    const int lane    = threadIdx.x & 63;
    const int wave_id = threadIdx.x >> 6;
    const int m       = lane & 15;
    const int q       = lane >> 4;
    float* __restrict__ myl = &lds[wave_id * 1024];

    const float b3s = b3[0];

    v8h a1[4];
    #pragma unroll
    for (int t = 0; t < 4; ++t)
        #pragma unroll
        for (int j = 0; j < 8; ++j)
            a1[t][j] = (_Float16)W1[(8 * q + j) * 64 + 16 * t + m];

    v8h a2[2][4];
    #pragma unroll
    for (int c = 0; c < 2; ++c)
        #pragma unroll
        for (int t = 0; t < 4; ++t)
            #pragma unroll
            for (int j = 0; j < 8; ++j)
                a2[c][t][j] = (_Float16)W2[(32 * c + 8 * q + j) * 64 + 16 * t + m];

    float bias1v[16], bias2v[16], w3v[16];
    #pragma unroll
    for (int t = 0; t < 4; ++t)
        #pragma unroll
        for (int r = 0; r < 4; ++r) {
            const int ch = 16 * t + 4 * q + r;
            bias1v[4 * t + r] = 256.0f * b1[ch];
            bias2v[4 * t + r] = 256.0f * b2[ch];
            w3v[4 * t + r]    = W3[ch];
        }

    const int nt = (n + 15) >> 4;
    const int stride = gridDim.x * 4;
    const int gw = blockIdx.x * 4 + wave_id;
    if (gw >= nt) return;

    v8h bh;
    {
        const int p0 = gw * 16;
        const int pr = (p0 + m < n) ? (p0 + m) : (n - 1);
        #pragma unroll
        for (int j = 0; j < 8; ++j)
            bh[j] = a_ws[(size_t)(8 * q + j) * n + pr];
    }

    for (int tile = gw; tile < nt; tile += stride) {
        const int p0 = tile * 16;

        v8h bhn = bh;
        const int nx = tile + stride;
        if (nx < nt) {
            const int p0n = nx * 16;
            const int prn = (p0n + m < n) ? (p0n + m) : (n - 1);
            #pragma unroll
            for (int j = 0; j < 8; ++j)
                bhn[j] = a_ws[(size_t)(8 * q + j) * n + prn];
        }

        v4f acc1[4];
        #pragma unroll
        for (int t = 0; t < 4; ++t) {
            #pragma unroll
            for (int r = 0; r < 4; ++r) acc1[t][r] = bias1v[4 * t + r];
            acc1[t] = __builtin_amdgcn_mfma_f32_16x16x32_f16(a1[t], bh, acc1[t], 0, 0, 0);
        }

        #pragma unroll
        for (int t = 0; t < 4; ++t)
            #pragma unroll
            for (int r = 0; r < 4; ++r)
                myl[(16 * t + 4 * q + r) * 16 + m] = fmaxf(acc1[t][r], 0.0f);
        __threadfence_block();

        v8h b2h[2];
        #pragma unroll
        for (int c = 0; c < 2; ++c)
            #pragma unroll
            for (int j = 0; j < 8; ++j)
                b2h[c][j] = (_Float16)myl[(32 * c + 8 * q + j) * 16 + m];

        v4f acc2[4];
        #pragma unroll
        for (int t = 0; t < 4; ++t) {
            #pragma unroll
            for (int r = 0; r < 4; ++r) acc2[t][r] = bias2v[4 * t + r];
            acc2[t] = __builtin_amdgcn_mfma_f32_16x16x32_f16(a2[0][t], b2h[0], acc2[t], 0, 0, 0);
            acc2[t] = __builtin_amdgcn_mfma_f32_16x16x32_f16(a2[1][t], b2h[1], acc2[t], 0, 0, 0);
        }

        float partial = 0.0f;
        #pragma unroll
        for (int t = 0; t < 4; ++t)
            #pragma unroll
            for (int r = 0; r < 4; ++r)
                partial = fmaf(fmaxf(acc2[t][r], 0.0f), w3v[4 * t + r], partial);

        partial += __shfl_xor(partial, 16);
        partial += __shfl_xor(partial, 32);

        if (q == 0 && p0 + m < n)
            out[pid[p0 + m]] = partial * (1.0f / 256.0f) + b3s;

        bh = bhn;
    }
}

// ==================== Fallback: round-4 fused kernel ====================
__global__ __launch_bounds__(256, 4)
void hashgrid_mlp_fused(const float* __restrict__ x,
                        const float* __restrict__ tables,
                        const float* __restrict__ resolutions,
                        const float* __restrict__ W1,
                        const float* __restrict__ b1,
                        const float* __restrict__ W2,
                        const float* __restrict__ b2,
                        const float* __restrict__ W3,
                        const float* __restrict__ b3,
                        float* __restrict__ out,
                        int n)
{
    const int i  = blockIdx.x * blockDim.x + threadIdx.x;
    const int ip = (i < n) ? i : (n - 1);

    const float x0 = x[3 * ip + 0] * 0.5f + 0.5f;
    const float x1 = x[3 * ip + 1] * 0.5f + 0.5f;
    const float x2 = x[3 * ip + 2] * 0.5f + 0.5f;

    float h1[64];
    #pragma unroll
    for (int j = 0; j < 64; ++j) h1[j] = b1[j];

    #pragma unroll
    for (int l = 0; l < N_LEVELS; ++l) {
        const float res = resolutions[l];
        const float px = x0 * res, py = x1 * res, pz = x2 * res;
        const float fx = floorf(px), fy = floorf(py), fz = floorf(pz);
        const float wx = px - fx, wy = py - fy, wz = pz - fz;
        const uint32_t cx = (uint32_t)fx;
        const uint32_t cy = (uint32_t)fy;
        const uint32_t cz = (uint32_t)fz;
        const uint32_t hx0 = cx,           hx1 = cx + 1u;
        const uint32_t hy0 = cy * PRIME_Y, hy1 = hy0 + PRIME_Y;
        const uint32_t hz0 = cz * PRIME_Z, hz1 = hz0 + PRIME_Z;
        const float wx0 = 1.0f - wx, wy0 = 1.0f - wy, wz0 = 1.0f - wz;
        const float* __restrict__ tab = tables + (size_t)l * (size_t)TABLE_SIZE * 2u;

        float f0 = 0.0f, f1 = 0.0f;
        #pragma unroll
        for (int c = 0; c < 8; ++c) {
            const uint32_t h = ((c & 1) ? hx1 : hx0) ^
                               ((c & 2) ? hy1 : hy0) ^
                               ((c & 4) ? hz1 : hz0);
            const uint32_t idx = h & (TABLE_SIZE - 1u);
            const float2 fv = *(const float2*)(tab + 2u * idx);
            const float wgt = ((c & 1) ? wx : wx0) *
                              ((c & 2) ? wy : wy0) *
                              ((c & 4) ? wz : wz0);
            f0 = fmaf(wgt, fv.x, f0);
            f1 = fmaf(wgt, fv.y, f1);
        }
        const float* __restrict__ w1a = W1 + (2 * l + 0) * 64;
        const float* __restrict__ w1b = W1 + (2 * l + 1) * 64;
        #pragma unroll
        for (int j = 0; j < 64; ++j)
            h1[j] = fmaf(f1, w1b[j], fmaf(f0, w1a[j], h1[j]));
    }

    #pragma unroll
    for (int j = 0; j < 64; ++j) h1[j] = fmaxf(h1[j], 0.0f);

    float accum = b3[0];
    #pragma unroll
    for (int half = 0; half < 2; ++half) {
        float h2[32];
        #pragma unroll
        for (int j = 0; j < 32; ++j) h2[j] = b2[half * 32 + j];
        #pragma unroll
        for (int k = 0; k < 64; ++k) {
            const float hk = h1[k];
            const float* __restrict__ w2row = W2 + k * 64 + half * 32;
            #pragma unroll
            for (int j = 0; j < 32; ++j)
                h2[j] = fmaf(hk, w2row[j], h2[j]);
        }
        #pragma unroll
        for (int j = 0; j < 32; ++j)
            accum = fmaf(fmaxf(h2[j], 0.0f), W3[half * 32 + j], accum);
    }
    out[ip] = accum;
}

extern "C" void kernel_launch(void* const* d_in, const int* in_sizes, int n_in,
                              void* d_out, int out_size, void* d_ws, size_t ws_size,
                              hipStream_t stream) {
    const float* x           = (const float*)d_in[0];
    const float* tables      = (const float*)d_in[1];
    const float* resolutions = (const float*)d_in[2];
    const float* W1          = (const float*)d_in[3];
    const float* b1          = (const float*)d_in[4];
    const float* W2          = (const float*)d_in[5];
    const float* b2          = (const float*)d_in[6];
    const float* W3          = (const float*)d_in[7];
    const float* b3          = (const float*)d_in[8];
    float* out               = (float*)d_out;

    const int n = out_size;  // 2,000,000
    const int block = 256;
    const int grid_pts = (n + block - 1) / block;
    const int chunk = (n + SORT_B - 1) / SORT_B;

    // ---- workspace layout ----
    // a_ws (128 MB) is written only by encode, AFTER the sort finishes, so
    // sort metadata (g_hist 34 MB + g_part 34 MB) aliases into it.
    size_t off = 0;
    #define CARVE(bytes) (off = (off + 255) & ~(size_t)255, off += (bytes), off - (bytes))
    const size_t aws_off   = CARVE((size_t)32 * n * sizeof(_Float16)); // 128 MB
    const size_t xs_off    = CARVE((size_t)3 * n * sizeof(float));     //  24 MB
    const size_t pid_off   = CARVE((size_t)n * sizeof(int));           //   8 MB
    const size_t tot_off   = CARVE((size_t)NB * sizeof(uint32_t));
    const size_t base_off  = CARVE((size_t)NB * sizeof(uint32_t));
    const size_t total_ws  = off;
    #undef CARVE

    if (ws_size >= total_ws) {
        char* ws = (char*)d_ws;
        _Float16* a_ws   = (_Float16*)(ws + aws_off);
        uint32_t* g_hist = (uint32_t*)(ws + aws_off);                          // alias
        uint32_t* g_part = (uint32_t*)(ws + aws_off + (size_t)SORT_B * NB * 4);// alias
        float*    xs     = (float*)(ws + xs_off);
        int*      pid    = (int*)(ws + pid_off);
        uint32_t* totals = (uint32_t*)(ws + tot_off);
        uint32_t* base   = (uint32_t*)(ws + base_off);

        hist_kernel<<<SORT_B, 256, 0, stream>>>(x, g_hist, n, chunk);
        scan_cols_kernel<<<NB / 256, 256, 0, stream>>>(g_hist, g_part, totals);
        scan_full_kernel<<<1, 1024, 0, stream>>>(totals, base);
        scatter_kernel<<<SORT_B, 256, 0, stream>>>(x, base, g_part, xs, pid, n, chunk);

        dim3 grid_enc(grid_pts, N_LEVELS);   // y = level, slow-varying
        encode_kernel<<<grid_enc, block, 0, stream>>>(xs, tables, resolutions, a_ws, n);
        mlp_mfma_kernel<<<1024, block, 0, stream>>>(a_ws, pid, W1, b1, W2, b2, W3, b3, out, n);
    } else {
        hashgrid_mlp_fused<<<grid_pts, block, 0, stream>>>(
            x, tables, resolutions, W1, b1, W2, b2, W3, b3, out, n);
    }
}

// Round 14
// 673.877 us; speedup vs baseline: 1.0313x; 1.0313x over previous
//
#include <hip/hip_runtime.h>
#include <hip/hip_bf16.h>
#include <stdint.h>

#define N_LEVELS   16
#define LOG2_T     19
#define TABLE_SIZE (1u << LOG2_T)
#define PRIME_Y    2654435761u
#define PRIME_Z    805459861u

#define NB        32768     // 32^3 buckets
#define SORT_B    256       // sort blocks (each owns a contiguous point chunk)

typedef float v4f __attribute__((ext_vector_type(4)));
typedef _Float16 v8h __attribute__((ext_vector_type(8)));

// ---------------- Morton key, 3x5 bits (bucketing only) ----------------
__device__ __forceinline__ uint32_t part1by2(uint32_t v) {
    v &= 0x3FFu;
    v = (v | (v << 16)) & 0x030000FFu;
    v = (v | (v <<  8)) & 0x0300F00Fu;
    v = (v | (v <<  4)) & 0x030C30C3u;
    v = (v | (v <<  2)) & 0x09249249u;
    return v;
}
__device__ __forceinline__ uint32_t morton_key(float xr, float yr, float zr) {
    int vx = (int)((xr * 0.5f + 0.5f) * 32.0f);
    int vy = (int)((yr * 0.5f + 0.5f) * 32.0f);
    int vz = (int)((zr * 0.5f + 0.5f) * 32.0f);
    vx = vx < 0 ? 0 : (vx > 31 ? 31 : vx);
    vy = vy < 0 ? 0 : (vy > 31 ? 31 : vy);
    vz = vz < 0 ? 0 : (vz > 31 ? 31 : vz);
    return part1by2((uint32_t)vx) | (part1by2((uint32_t)vy) << 1)
         | (part1by2((uint32_t)vz) << 2);   // 15-bit key
}

// ============== sort, NO device atomics (LDS-histogram counting sort) =====
__global__ __launch_bounds__(256)
void hist_kernel(const float* __restrict__ x, uint32_t* __restrict__ g_hist,
                 int n, int chunk)
{
    __shared__ uint32_t pack[NB / 2];
    const int b = blockIdx.x, t = threadIdx.x;
    for (int w = t; w < NB / 2; w += 256) pack[w] = 0;
    __syncthreads();
    const int beg = b * chunk;
    const int end = (beg + chunk < n) ? (beg + chunk) : n;
    for (int i = beg + t; i < end; i += 256) {
        const uint32_t key = morton_key(x[3*i], x[3*i+1], x[3*i+2]);
        atomicAdd(&pack[key >> 1], 1u << ((key & 1u) << 4));
    }
    __syncthreads();
    uint32_t* __restrict__ dst = g_hist + (size_t)b * NB;
    for (int w = t; w < NB / 2; w += 256) {
        const uint32_t p = pack[w];
        dst[2*w]     = p & 0xFFFFu;
        dst[2*w + 1] = p >> 16;
    }
}

// column scan: part[b][key] = sum_{b'<b} hist[b'][key]; totals[key] = full sum
__global__ __launch_bounds__(256)
void scan_cols_kernel(const uint32_t* __restrict__ g_hist,
                      uint32_t* __restrict__ g_part,
                      uint32_t* __restrict__ totals)
{
    const int key = blockIdx.x * 256 + threadIdx.x;   // 0..NB-1
    uint32_t run = 0;
    #pragma unroll 8
    for (int b = 0; b < SORT_B; ++b) {
        const size_t idx = (size_t)b * NB + key;
        const uint32_t v = g_hist[idx];
        g_part[idx] = run;
        run += v;
    }
    totals[key] = run;
}

__global__ void scan_block_kernel(const uint32_t* __restrict__ counts,
                                  uint32_t* __restrict__ prefix,
                                  uint32_t* __restrict__ blocksum) {
    __shared__ uint32_t s[256];
    const int t = threadIdx.x;
    const int i = blockIdx.x * 256 + t;
    const uint32_t v = counts[i];
    s[t] = v; __syncthreads();
    #pragma unroll
    for (int d = 1; d < 256; d <<= 1) {
        const uint32_t u = (t >= d) ? s[t - d] : 0;
        __syncthreads();
        s[t] += u;
        __syncthreads();
    }
    prefix[i] = s[t] - v;
    if (t == 255) blocksum[blockIdx.x] = s[255];
}

__global__ void scan_top_kernel(const uint32_t* __restrict__ blocksum,
                                uint32_t* __restrict__ blockbase, int nb) {
    __shared__ uint32_t s[1024];
    const int t = threadIdx.x;
    const uint32_t v = (t < nb) ? blocksum[t] : 0;
    s[t] = v; __syncthreads();
    #pragma unroll
    for (int d = 1; d < 1024; d <<= 1) {
        const uint32_t u = (t >= d) ? s[t - d] : 0;
        __syncthreads();
        s[t] += u;
        __syncthreads();
    }
    if (t < nb) blockbase[t] = s[t] - v;
}

__global__ void addback_kernel(const uint32_t* __restrict__ prefix,
                               const uint32_t* __restrict__ blockbase,
                               uint32_t* __restrict__ base) {
    const int i = blockIdx.x * 256 + threadIdx.x;
    base[i] = prefix[i] + blockbase[i >> 8];
}

// scatter: rank from LDS counters (same packed scheme), pos = base+part+rank.
// Writes xs (SoA) + rank_inv (coalesced by original index).
__global__ __launch_bounds__(256)
void scatter_kernel(const float* __restrict__ x,
                    const uint32_t* __restrict__ base,
                    const uint32_t* __restrict__ g_part,
                    float* __restrict__ xs,        // [3][N]
                    int* __restrict__ rank_inv,    // [N] orig -> sorted pos
                    int n, int chunk)
{
    __shared__ uint32_t pack[NB / 2];
    const int b = blockIdx.x, t = threadIdx.x;
    for (int w = t; w < NB / 2; w += 256) pack[w] = 0;
    __syncthreads();
    const uint32_t* __restrict__ part = g_part + (size_t)b * NB;
    const int beg = b * chunk;
    const int end = (beg + chunk < n) ? (beg + chunk) : n;
    for (int i = beg + t; i < end; i += 256) {
        const float a = x[3*i], c = x[3*i+1], d = x[3*i+2];
        const uint32_t key = morton_key(a, c, d);
        const uint32_t sh = (key & 1u) << 4;
        uint32_t r = atomicAdd(&pack[key >> 1], 1u << sh);
        r = (r >> sh) & 0xFFFFu;
        const uint32_t pos = base[key] + part[key] + r;
        xs[pos]         = a;
        xs[n + pos]     = c;
        xs[2*n + pos]   = d;
        rank_inv[i]     = (int)pos;
    }
}

// ============================ encode ============================
// Level-major + x-corner pair merging over Morton-sorted points; f16 x256
// output. At the L2 request-rate floor: ~105M merged requests / 128 req/cyc
// / 2.4 GHz = ~342 us (validated R7/R8/R10-R13).
__global__ __launch_bounds__(256, 8)
void encode_kernel(const float* __restrict__ xs,          // [3][N] sorted
                   const float* __restrict__ tables,      // [16, T, 2]
                   const float* __restrict__ resolutions, // [16]
                   _Float16* __restrict__ a_ws,           // [32][N] f16, x256
                   int n)
{
    const int l = blockIdx.y;
    int p = blockIdx.x * blockDim.x + threadIdx.x;
    if (p >= n) p = n - 1;

    const float x0 = xs[p]       * 0.5f + 0.5f;
    const float x1 = xs[n + p]   * 0.5f + 0.5f;
    const float x2 = xs[2*n + p] * 0.5f + 0.5f;

    const float res = resolutions[l];
    const float px = x0 * res, py = x1 * res, pz = x2 * res;
    const float fx = floorf(px), fy = floorf(py), fz = floorf(pz);
    const float wx = px - fx, wy = py - fy, wz = pz - fz;
    const uint32_t cx = (uint32_t)fx;
    const uint32_t cy = (uint32_t)fy;
    const uint32_t cz = (uint32_t)fz;

    const uint32_t hy0 = cy * PRIME_Y, hy1 = hy0 + PRIME_Y;
    const uint32_t hz0 = cz * PRIME_Z, hz1 = hz0 + PRIME_Z;

    const float wx0 = 1.0f - wx, wy0 = 1.0f - wy, wz0 = 1.0f - wz;

    const float* __restrict__ tab = tables + (size_t)l * (size_t)TABLE_SIZE * 2u;

    const uint32_t hyz[4] = { hy0 ^ hz0, hy1 ^ hz0, hy0 ^ hz1, hy1 ^ hz1 };

    float2 cva[4], cvb[4];

    if ((cx & 1u) == 0u) {
        #pragma unroll
        for (int q = 0; q < 4; ++q) {
            const uint32_t idx_a = (cx ^ hyz[q]) & (TABLE_SIZE - 1u);
            const uint32_t base  = idx_a & ~1u;
            const float4 f4 = *(const float4*)(tab + 2u * base);
            const bool hi = (idx_a & 1u) != 0u;
            cva[q] = hi ? make_float2(f4.z, f4.w) : make_float2(f4.x, f4.y);
            cvb[q] = hi ? make_float2(f4.x, f4.y) : make_float2(f4.z, f4.w);
        }
    } else {
        const uint32_t hx0 = cx, hx1 = cx + 1u;
        #pragma unroll
        for (int q = 0; q < 4; ++q) {
            const uint32_t idx_a = (hx0 ^ hyz[q]) & (TABLE_SIZE - 1u);
            const uint32_t idx_b = (hx1 ^ hyz[q]) & (TABLE_SIZE - 1u);
            cva[q] = *(const float2*)(tab + 2u * idx_a);
            cvb[q] = *(const float2*)(tab + 2u * idx_b);
        }
    }

    float f0 = 0.0f, f1 = 0.0f;
    #pragma unroll
    for (int q = 0; q < 4; ++q) {
        const float yf = (q & 1) ? wy : wy0;
        const float zf = (q & 2) ? wz : wz0;
        const float wgt_a = (wx0 * yf) * zf;
        const float wgt_b = (wx  * yf) * zf;
        f0 = fmaf(wgt_a, cva[q].x, f0);
        f1 = fmaf(wgt_a, cva[q].y, f1);
        f0 = fmaf(wgt_b, cvb[q].x, f0);
        f1 = fmaf(wgt_b, cvb[q].y, f1);
    }

    a_ws[(size_t)(2 * l + 0) * n + p] = (_Float16)(f0 * 256.0f);
    a_ws[(size_t)(2 * l + 1) * n + p] = (_Float16)(f1 * 256.0f);
}

// ============================ MFMA MLP ============================
// 16 points/wave-tile; weights in A-frags preloaded once; f16 a_ws direct
// into B-frags; software-pipelined tile loop; coalesced sorted-order write.
__global__ __launch_bounds__(256, 2)
void mlp_mfma_kernel(const _Float16* __restrict__ a_ws,  // [32][N] f16 x256
                     const float* __restrict__ W1,
                     const float* __restrict__ b1,
                     const float* __restrict__ W2,
                     const float* __restrict__ b2,
                     const float* __restrict__ W3,
                     const float* __restrict__ b3,
                     float* __restrict__ outs,           // [N] sorted order
                     int n)
{
    __shared__ float lds[4 * 64 * 16];

    const int lane    = threadIdx.x & 63;
    const int wave_id = threadIdx.x >> 6;
    const int m       = lane & 15;
    const int q       = lane >> 4;
    float* __restrict__ myl = &lds[wave_id * 1024];

    const float b3s = b3[0];

    v8h a1[4];
    #pragma unroll
    for (int t = 0; t < 4; ++t)
        #pragma unroll
        for (int j = 0; j < 8; ++j)
            a1[t][j] = (_Float16)W1[(8 * q + j) * 64 + 16 * t + m];

    v8h a2[2][4];
    #pragma unroll
    for (int c = 0; c < 2; ++c)
        #pragma unroll
        for (int t = 0; t < 4; ++t)
            #pragma unroll
            for (int j = 0; j < 8; ++j)
                a2[c][t][j] = (_Float16)W2[(32 * c + 8 * q + j) * 64 + 16 * t + m];

    float bias1v[16], bias2v[16], w3v[16];
    #pragma unroll
    for (int t = 0; t < 4; ++t)
        #pragma unroll
        for (int r = 0; r < 4; ++r) {
            const int ch = 16 * t + 4 * q + r;
            bias1v[4 * t + r] = 256.0f * b1[ch];
            bias2v[4 * t + r] = 256.0f * b2[ch];
            w3v[4 * t + r]    = W3[ch];
        }

    const int nt = (n + 15) >> 4;
    const int stride = gridDim.x * 4;
    const int gw = blockIdx.x * 4 + wave_id;
    if (gw >= nt) return;

    v8h bh;
    {
        const int p0 = gw * 16;
        const int pr = (p0 + m < n) ? (p0 + m) : (n - 1);
        #pragma unroll
        for (int j = 0; j < 8; ++j)
            bh[j] = a_ws[(size_t)(8 * q + j) * n + pr];
    }

    for (int tile = gw; tile < nt; tile += stride) {
        const int p0 = tile * 16;

        v8h bhn = bh;
        const int nx = tile + stride;
        if (nx < nt) {
            const int p0n = nx * 16;
            const int prn = (p0n + m < n) ? (p0n + m) : (n - 1);
            #pragma unroll
            for (int j = 0; j < 8; ++j)
                bhn[j] = a_ws[(size_t)(8 * q + j) * n + prn];
        }

        v4f acc1[4];
        #pragma unroll
        for (int t = 0; t < 4; ++t) {
            #pragma unroll
            for (int r = 0; r < 4; ++r) acc1[t][r] = bias1v[4 * t + r];
            acc1[t] = __builtin_amdgcn_mfma_f32_16x16x32_f16(a1[t], bh, acc1[t], 0, 0, 0);
        }

        #pragma unroll
        for (int t = 0; t < 4; ++t)
            #pragma unroll
            for (int r = 0; r < 4; ++r)
                myl[(16 * t + 4 * q + r) * 16 + m] = fmaxf(acc1[t][r], 0.0f);
        __threadfence_block();

        v8h b2h[2];
        #pragma unroll
        for (int c = 0; c < 2; ++c)
            #pragma unroll
            for (int j = 0; j < 8; ++j)
                b2h[c][j] = (_Float16)myl[(32 * c + 8 * q + j) * 16 + m];

        v4f acc2[4];
        #pragma unroll
        for (int t = 0; t < 4; ++t) {
            #pragma unroll
            for (int r = 0; r < 4; ++r) acc2[t][r] = bias2v[4 * t + r];
            acc2[t] = __builtin_amdgcn_mfma_f32_16x16x32_f16(a2[0][t], b2h[0], acc2[t], 0, 0, 0);
            acc2[t] = __builtin_amdgcn_mfma_f32_16x16x32_f16(a2[1][t], b2h[1], acc2[t], 0, 0, 0);
        }

        float partial = 0.0f;
        #pragma unroll
        for (int t = 0; t < 4; ++t)
            #pragma unroll
            for (int r = 0; r < 4; ++r)
                partial = fmaf(fmaxf(acc2[t][r], 0.0f), w3v[4 * t + r], partial);

        partial += __shfl_xor(partial, 16);
        partial += __shfl_xor(partial, 32);

        if (q == 0 && p0 + m < n)
            outs[p0 + m] = partial * (1.0f / 256.0f) + b3s;

        bh = bhn;
    }
}

// out[i] = outs[rank_inv[i]] : coalesced write, random 4B gather (cheap)
__global__ void unscatter_kernel(const float* __restrict__ outs,
                                 const int* __restrict__ rank_inv,
                                 float* __restrict__ out, int n) {
    const int i = blockIdx.x * blockDim.x + threadIdx.x;
    if (i < n) out[i] = outs[rank_inv[i]];
}

// ==================== Fallback: round-4 fused kernel ====================
__global__ __launch_bounds__(256, 4)
void hashgrid_mlp_fused(const float* __restrict__ x,
                        const float* __restrict__ tables,
                        const float* __restrict__ resolutions,
                        const float* __restrict__ W1,
                        const float* __restrict__ b1,
                        const float* __restrict__ W2,
                        const float* __restrict__ b2,
                        const float* __restrict__ W3,
                        const float* __restrict__ b3,
                        float* __restrict__ out,
                        int n)
{
    const int i  = blockIdx.x * blockDim.x + threadIdx.x;
    const int ip = (i < n) ? i : (n - 1);

    const float x0 = x[3 * ip + 0] * 0.5f + 0.5f;
    const float x1 = x[3 * ip + 1] * 0.5f + 0.5f;
    const float x2 = x[3 * ip + 2] * 0.5f + 0.5f;

    float h1[64];
    #pragma unroll
    for (int j = 0; j < 64; ++j) h1[j] = b1[j];

    #pragma unroll
    for (int l = 0; l < N_LEVELS; ++l) {
        const float res = resolutions[l];
        const float px = x0 * res, py = x1 * res, pz = x2 * res;
        const float fx = floorf(px), fy = floorf(py), fz = floorf(pz);
        const float wx = px - fx, wy = py - fy, wz = pz - fz;
        const uint32_t cx = (uint32_t)fx;
        const uint32_t cy = (uint32_t)fy;
        const uint32_t cz = (uint32_t)fz;
        const uint32_t hx0 = cx,           hx1 = cx + 1u;
        const uint32_t hy0 = cy * PRIME_Y, hy1 = hy0 + PRIME_Y;
        const uint32_t hz0 = cz * PRIME_Z, hz1 = hz0 + PRIME_Z;
        const float wx0 = 1.0f - wx, wy0 = 1.0f - wy, wz0 = 1.0f - wz;
        const float* __restrict__ tab = tables + (size_t)l * (size_t)TABLE_SIZE * 2u;

        float f0 = 0.0f, f1 = 0.0f;
        #pragma unroll
        for (int c = 0; c < 8; ++c) {
            const uint32_t h = ((c & 1) ? hx1 : hx0) ^
                               ((c & 2) ? hy1 : hy0) ^
                               ((c & 4) ? hz1 : hz0);
            const uint32_t idx = h & (TABLE_SIZE - 1u);
            const float2 fv = *(const float2*)(tab + 2u * idx);
            const float wgt = ((c & 1) ? wx : wx0) *
                              ((c & 2) ? wy : wy0) *
                              ((c & 4) ? wz : wz0);
            f0 = fmaf(wgt, fv.x, f0);
            f1 = fmaf(wgt, fv.y, f1);
        }
        const float* __restrict__ w1a = W1 + (2 * l + 0) * 64;
        const float* __restrict__ w1b = W1 + (2 * l + 1) * 64;
        #pragma unroll
        for (int j = 0; j < 64; ++j)
            h1[j] = fmaf(f1, w1b[j], fmaf(f0, w1a[j], h1[j]));
    }

    #pragma unroll
    for (int j = 0; j < 64; ++j) h1[j] = fmaxf(h1[j], 0.0f);

    float accum = b3[0];
    #pragma unroll
    for (int half = 0; half < 2; ++half) {
        float h2[32];
        #pragma unroll
        for (int j = 0; j < 32; ++j) h2[j] = b2[half * 32 + j];
        #pragma unroll
        for (int k = 0; k < 64; ++k) {
            const float hk = h1[k];
            const float* __restrict__ w2row = W2 + k * 64 + half * 32;
            #pragma unroll
            for (int j = 0; j < 32; ++j)
                h2[j] = fmaf(hk, w2row[j], h2[j]);
        }
        #pragma unroll
        for (int j = 0; j < 32; ++j)
            accum = fmaf(fmaxf(h2[j], 0.0f), W3[half * 32 + j], accum);
    }
    out[ip] = accum;
}

extern "C" void kernel_launch(void* const* d_in, const int* in_sizes, int n_in,
                              void* d_out, int out_size, void* d_ws, size_t ws_size,
                              hipStream_t stream) {
    const float* x           = (const float*)d_in[0];
    const float* tables      = (const float*)d_in[1];
    const float* resolutions = (const float*)d_in[2];
    const float* W1          = (const float*)d_in[3];
    const float* b1          = (const float*)d_in[4];
    const float* W2          = (const float*)d_in[5];
    const float* b2          = (const float*)d_in[6];
    const float* W3          = (const float*)d_in[7];
    const float* b3          = (const float*)d_in[8];
    float* out               = (float*)d_out;

    const int n = out_size;  // 2,000,000
    const int block = 256;
    const int grid_pts = (n + block - 1) / block;
    const int chunk = (n + SORT_B - 1) / SORT_B;

    // ---- workspace layout ----
    // a_ws (128 MB) is written only by encode, AFTER the sort finishes, so
    // the sort's metadata (g_hist 34 MB + g_part 34 MB) aliases into it.
    size_t off = 0;
    #define CARVE(bytes) (off = (off + 255) & ~(size_t)255, off += (bytes), off - (bytes))
    const size_t aws_off   = CARVE((size_t)32 * n * sizeof(_Float16)); // 128 MB
    const size_t xs_off    = CARVE((size_t)3 * n * sizeof(float));     //  24 MB
    const size_t rank_off  = CARVE((size_t)n * sizeof(int));           //   8 MB
    const size_t outs_off  = CARVE((size_t)n * sizeof(float));         //   8 MB
    const size_t tot_off   = CARVE((size_t)NB * sizeof(uint32_t));
    const size_t pref_off  = CARVE((size_t)NB * sizeof(uint32_t));
    const size_t base_off  = CARVE((size_t)NB * sizeof(uint32_t));
    const size_t bsum_off  = CARVE(1024 * sizeof(uint32_t));
    const size_t bbase_off = CARVE(1024 * sizeof(uint32_t));
    const size_t total_ws  = off;
    #undef CARVE

    if (ws_size >= total_ws) {
        char* ws = (char*)d_ws;
        _Float16* a_ws   = (_Float16*)(ws + aws_off);
        uint32_t* g_hist = (uint32_t*)(ws + aws_off);                          // alias
        uint32_t* g_part = (uint32_t*)(ws + aws_off + (size_t)SORT_B * NB * 4);// alias
        float*    xs     = (float*)(ws + xs_off);
        int*      rank   = (int*)(ws + rank_off);
        float*    outs   = (float*)(ws + outs_off);
        uint32_t* totals = (uint32_t*)(ws + tot_off);
        uint32_t* pref   = (uint32_t*)(ws + pref_off);
        uint32_t* base   = (uint32_t*)(ws + base_off);
        uint32_t* bsum   = (uint32_t*)(ws + bsum_off);
        uint32_t* bbase  = (uint32_t*)(ws + bbase_off);

        hist_kernel<<<SORT_B, block, 0, stream>>>(x, g_hist, n, chunk);
        scan_cols_kernel<<<NB / 256, block, 0, stream>>>(g_hist, g_part, totals);
        scan_block_kernel<<<NB / 256, block, 0, stream>>>(totals, pref, bsum);
        scan_top_kernel<<<1, 1024, 0, stream>>>(bsum, bbase, NB / 256);
        addback_kernel<<<NB / 256, block, 0, stream>>>(pref, bbase, base);
        scatter_kernel<<<SORT_B, block, 0, stream>>>(x, base, g_part, xs, rank, n, chunk);

        dim3 grid_enc(grid_pts, N_LEVELS);   // y = level, slow-varying
        encode_kernel<<<grid_enc, block, 0, stream>>>(xs, tables, resolutions, a_ws, n);
        mlp_mfma_kernel<<<1024, block, 0, stream>>>(a_ws, W1, b1, W2, b2, W3, b3, outs, n);
        unscatter_kernel<<<grid_pts, block, 0, stream>>>(outs, rank, out, n);
    } else {
        hashgrid_mlp_fused<<<grid_pts, block, 0, stream>>>(
            x, tables, resolutions, W1, b1, W2, b2, W3, b3, out, n);
    }
}